// Round 11
// baseline (1762.797 us; speedup 1.0000x reference)
//
#include <hip/hip_runtime.h>
#include <hip/hip_bf16.h>
#include <cstdio>
#include <cstdint>

// ---------------- model dims ----------------
#define E_    1280
#define L_    4
#define NH_   16
#define D_    80
#define DP_   96      // D padded to mult of 32 for QK^T K-loop
#define MLP_  5120
#define O_    2048
#define S_    2048
#define H4_   5120
#define INP_  1536

typedef __attribute__((ext_vector_type(4))) float f32x4;
typedef __attribute__((ext_vector_type(8))) short short8v;
typedef __attribute__((ext_vector_type(4))) short short4v;

__device__ __forceinline__ short f2bf(float f){
  uint32_t u = __float_as_uint(f);
  uint32_t r = (u + 0x7FFFu + ((u >> 16) & 1u)) >> 16;   // RNE
  return (short)r;
}
__device__ __forceinline__ float bf2f(short s){
  return __uint_as_float(((uint32_t)(uint16_t)s) << 16);
}
__device__ __forceinline__ float gelu_tanh(float x){
  const float z = 0.7978845608028654f*(x + 0.044715f*x*x*x);
  const float e = __expf(2.f*z);
  return 0.5f*x*(1.f + (e-1.f)/(e+1.f));
}
__device__ __forceinline__ float gelu_erf(float x){
  return 0.5f*x*(1.f + erff(x*0.7071067811865476f));
}
__device__ __forceinline__ void token_hw(int t, int& hc, int& wc){
  hc = ((t>>1)&1) + ((t>>6)<<1);
  wc = (t&1)      + (((t>>2)&15)<<1);
}
__device__ __forceinline__ void gload16(const short* g, short* l){
  __builtin_amdgcn_global_load_lds((const __attribute__((address_space(1))) void*)g,
                                   (__attribute__((address_space(3))) void*)l, 16, 0, 0);
}

// ---------------- f32 -> bf16 bulk convert (only x needs it now) ----------------
__global__ __launch_bounds__(256)
void cvt_k(const float* __restrict__ src, short* __restrict__ dst, long long n)
{
  const long long stride = (long long)gridDim.x*256*8;
  for (long long i = ((long long)blockIdx.x*256 + threadIdx.x)*8; i < n; i += stride){
    float4 v0 = *(const float4*)(src+i);
    float4 v1 = *(const float4*)(src+i+4);
    short8v w;
    w[0]=f2bf(v0.x); w[1]=f2bf(v0.y); w[2]=f2bf(v0.z); w[3]=f2bf(v0.w);
    w[4]=f2bf(v1.x); w[5]=f2bf(v1.y); w[6]=f2bf(v1.z); w[7]=f2bf(v1.w);
    *(short8v*)(dst+i) = w;
  }
}

// ---------------- GEMM: A bf16 via gload_lds (swizzled source), B f32 reg-staged ----------
// C[m][n] = epi( sum_k A[m][k]*B[n][k] + bias[n] ) (+ residual from C)
// A:(M,K) bf16 row-major, B:(N,K) f32 row-major (weights read directly, cvt in-kernel).
// Requires M%128==0, N%128==0, (K/kSplit)%32==0 (all call sites satisfy this).
// LDS tile = 512 x 16B chunks; swizzle sigma(c)=c^((c>>3)&7) (involution).
// RACE-FIX vs R10: stageA(t+2) is issued AFTER barrier(t) (its target buffer
// (t-1)%3 is read at iter t-1; barrier(t) guarantees those reads completed —
// each wave's MFMAs consumed them before it could reach barrier(t)).
// writeB((t+1)%3) stays pre-barrier (target last read at iter t-2; separated
// by barrier(t-1)). vmcnt ledger (in-order retirement):
//   prologue: [lB0(4), sA0(2)] -> vmcnt(2) retires lB0 exactly.
//   steady top-of-iter: [sA(t)(2), lB(t+1)(4), sA(t+1)(2)] -> vmcnt(2)
//   retires sA(t)+lB(t+1) exactly; last iter: vmcnt(0).
struct Gemm2P {
  const short* A; const float* B; void* C;
  const float* bias;
  short* part;                  // split-K partial buffer [kSplit][M][N] bf16
  int lda, ldb, ldc, M, N, K;
  float scale;
  int kSplit;
};

template<int EPI, bool RES, bool CF32, bool SPLIT>   // EPI: 0=none,1=gelu_tanh,2=gelu_erf
__global__ __launch_bounds__(256)
void gemm2_k(Gemm2P p)
{
  __shared__ short As[3][4096];   // [buf][512 chunks x 8 shorts]
  __shared__ short Bs[3][4096];

  int ks = 0;
  if constexpr (SPLIT){ ks = blockIdx.z; }

  // bijective XCD swizzle on the tile plane (m204)
  const int nwg = gridDim.x*gridDim.y;
  const int orig = blockIdx.y*gridDim.x + blockIdx.x;
  const int q8 = nwg >> 3, r8 = nwg & 7;
  const int xcd = orig & 7, oidx = orig >> 3;
  const int wg = (xcd < r8 ? xcd*(q8+1) : r8*(q8+1) + (xcd-r8)*q8) + oidx;
  const int nt = wg % gridDim.x, mt = wg / gridDim.x;

  const int tid = threadIdx.x, lane = tid & 63, wv = tid >> 6;
  const int Kp  = SPLIT ? p.K / p.kSplit : p.K;
  const int kBeg = SPLIT ? ks * Kp : 0;

  // A staging (gload_lds): linear LDS dest, inverse-sigma global source
  const int lam = lane ^ ((lane >> 3) & 7);
  const int asr = lam >> 2, asc = (lam & 3) * 8;
  const short* pa0 = p.A + (long long)(mt*128 + (wv*2+0)*16 + asr)*p.lda + asc + kBeg;
  const short* pa1 = p.A + (long long)(mt*128 + (wv*2+1)*16 + asr)*p.lda + asc + kBeg;
  const int so0 = (wv*2+0)*512;
  const int so1 = (wv*2+1)*512;

  // B staging (f32 regs): linear coalesced global read, sigma-indexed ds_write
  const int bsr = lane >> 2, bcc = lane & 3;
  const int brow0 = (wv*2+0)*16 + bsr, brow1 = (wv*2+1)*16 + bsr;
  const float* pbf0 = p.B + (long long)(nt*128 + brow0)*p.ldb + bcc*8 + kBeg;
  const float* pbf1 = p.B + (long long)(nt*128 + brow1)*p.ldb + bcc*8 + kBeg;
  const int wch0 = ((brow0*4 + bcc) ^ ((brow0>>1)&7)) * 8;   // shorts
  const int wch1 = ((brow1*4 + bcc) ^ ((brow1>>1)&7)) * 8;

  const int fr = lane & 15, g4 = lane >> 4;
  const int wr = (wv >> 1) * 64, wc = (wv & 1) * 64;

  f32x4 acc[4][4] = {};
  float4 br0, br1, br2, br3;     // B f32 staging regs (one K-step: 2 segs x 8 floats)

  auto loadB = [&](int t){
    const int k0 = t << 5;
    br0 = *(const float4*)(pbf0 + k0);
    br1 = *(const float4*)(pbf0 + k0 + 4);
    br2 = *(const float4*)(pbf1 + k0);
    br3 = *(const float4*)(pbf1 + k0 + 4);
  };
  auto stageA = [&](int buf, int t){
    const int k0 = t << 5;
    gload16(pa0 + k0, &As[buf][so0]);
    gload16(pa1 + k0, &As[buf][so1]);
  };
  auto writeB = [&](int buf){
    short8v w0, w1;
    w0[0]=f2bf(br0.x); w0[1]=f2bf(br0.y); w0[2]=f2bf(br0.z); w0[3]=f2bf(br0.w);
    w0[4]=f2bf(br1.x); w0[5]=f2bf(br1.y); w0[6]=f2bf(br1.z); w0[7]=f2bf(br1.w);
    w1[0]=f2bf(br2.x); w1[1]=f2bf(br2.y); w1[2]=f2bf(br2.z); w1[3]=f2bf(br2.w);
    w1[4]=f2bf(br3.x); w1[5]=f2bf(br3.y); w1[6]=f2bf(br3.z); w1[7]=f2bf(br3.w);
    *(short8v*)&Bs[buf][wch0] = w0;
    *(short8v*)&Bs[buf][wch1] = w1;
  };

  const int ntile = Kp >> 5;
  // prologue: B0 -> regs, A0 -> LDS(buf0); B0 -> LDS; prefetch B1 regs, A1 -> LDS(buf1)
  loadB(0);
  stageA(0, 0);
  asm volatile("s_waitcnt vmcnt(2)" ::: "memory");   // retires loadB(0) exactly
  writeB(0);
  if (ntile > 1){ loadB(1); stageA(1, 1); }

  for (int t = 0; t < ntile; t++){
    const int cur = t % 3;
    if (t + 1 < ntile) { asm volatile("s_waitcnt vmcnt(2)" ::: "memory"); }  // A(t) in LDS, B(t+1) regs
    else               { asm volatile("s_waitcnt vmcnt(0)" ::: "memory"); }
    if (t + 1 < ntile) writeB((t+1) % 3);   // buf last read at iter t-2: barrier(t-1) separates
    if (t + 2 < ntile) loadB(t+2);          // register loads; compiler-tracked deps
    asm volatile("s_waitcnt lgkmcnt(0)" ::: "memory");   // my ds_writes visible
    __builtin_amdgcn_s_barrier();
    asm volatile("" ::: "memory");
    short8v a[4], b[4];
    #pragma unroll
    for (int i=0;i<4;i++){
      const int ra = wr + i*16 + fr;
      const int ca = (ra*4 + g4) ^ ((ra>>1)&7);
      a[i] = *(const short8v*)&As[cur][ca*8];
      const int rb = wc + i*16 + fr;
      const int cb = (rb*4 + g4) ^ ((rb>>1)&7);
      b[i] = *(const short8v*)&Bs[cur][cb*8];
    }
    if (t + 2 < ntile) stageA((t+2)%3, t+2);   // POST-barrier: target buf read at t-1, reads done by barrier(t)
    #pragma unroll
    for (int i=0;i<4;i++)
      #pragma unroll
      for (int j=0;j<4;j++)
        acc[i][j] = __builtin_amdgcn_mfma_f32_16x16x32_bf16(a[i], b[j], acc[i][j], 0, 0, 0);
  }

  #pragma unroll
  for (int i=0;i<4;i++){
    #pragma unroll
    for (int j=0;j<4;j++){
      #pragma unroll
      for (int r=0;r<4;r++){
        const int row = mt*128 + wr + i*16 + g4*4 + r;
        const int col = nt*128 + wc + j*16 + fr;
        float v = acc[i][j][r];
        if constexpr (SPLIT){
          p.part[((long long)ks*p.M + row)*p.N + col] = f2bf(v);
        } else {
          if (p.bias) v += p.bias[col];
          if constexpr (EPI==1) v = gelu_tanh(v);
          if constexpr (EPI==2) v = gelu_erf(v);
          const long long off = (long long)row*p.ldc + col;
          if constexpr (RES)  v += ((const float*)p.C)[off];
          if constexpr (CF32) ((float*)p.C)[off] = v;
          else                ((short*)p.C)[off] = f2bf(v);
        }
      }
    }
  }
}

// ---------------- split-K reduce (C contiguous, ldc == N), bf16 partials ----------------
template<int EPI, bool RES, bool CF32>
__global__ __launch_bounds__(256)
void reduce_k(const short* __restrict__ part, int kSplit, long long MN, int N,
              const float* __restrict__ bias, void* __restrict__ C)
{
  const long long i = ((long long)blockIdx.x*256 + threadIdx.x)*8;
  if (i >= MN) return;
  float v[8];
  { short8v pv = *(const short8v*)(part + i);
    #pragma unroll
    for (int e=0;e<8;e++) v[e] = bf2f(pv[e]); }
  for (int ks = 1; ks < kSplit; ks++){
    short8v pv = *(const short8v*)(part + (long long)ks*MN + i);
    #pragma unroll
    for (int e=0;e<8;e++) v[e] += bf2f(pv[e]);
  }
  if (bias){
    const int col = (int)(i % N);
    #pragma unroll
    for (int e=0;e<8;e++) v[e] += bias[col+e];
  }
  #pragma unroll
  for (int e=0;e<8;e++){
    if constexpr (EPI==1) v[e] = gelu_tanh(v[e]);
    if constexpr (EPI==2) v[e] = gelu_erf(v[e]);
  }
  if constexpr (RES){
    const float* cp = (const float*)C + i;
    #pragma unroll
    for (int e=0;e<8;e++) v[e] += cp[e];
  }
  if constexpr (CF32){
    float4 o0 = {v[0],v[1],v[2],v[3]}, o1 = {v[4],v[5],v[6],v[7]};
    *(float4*)((float*)C + i) = o0;
    *(float4*)((float*)C + i + 4) = o1;
  } else {
    short8v o;
    #pragma unroll
    for (int e=0;e<8;e++) o[e] = f2bf(v[e]);
    *(short8v*)((short*)C + i) = o;
  }
}

// ---------------- fused split-K(4) reduce + residual + LayerNorm (rows of E) ----------------
__global__ __launch_bounds__(256)
void redln_k(const short* __restrict__ part, long long MN, const float* __restrict__ bias,
             float* __restrict__ h, const float* __restrict__ lnw, const float* __restrict__ lnb,
             short* __restrict__ aln)
{
  __shared__ float red[8];
  const int row = blockIdx.x, tid = threadIdx.x;
  float4 vals[2];
  float s = 0.f, sq = 0.f;
  #pragma unroll
  for (int it=0; it<2; it++){
    const int c = tid*4 + it*1024;
    if (c < E_){
      float4 v = *(const float4*)(h + (long long)row*E_ + c);
      const float4 b = *(const float4*)(bias + c);
      v.x += b.x; v.y += b.y; v.z += b.z; v.w += b.w;
      #pragma unroll
      for (int ks=0; ks<4; ks++){
        short4v pv = *(const short4v*)(part + (long long)ks*MN + (long long)row*E_ + c);
        v.x += bf2f(pv[0]); v.y += bf2f(pv[1]); v.z += bf2f(pv[2]); v.w += bf2f(pv[3]);
      }
      *(float4*)(h + (long long)row*E_ + c) = v;
      vals[it] = v;
      s  += v.x+v.y+v.z+v.w;
      sq += v.x*v.x+v.y*v.y+v.z*v.z+v.w*v.w;
    }
  }
  #pragma unroll
  for (int m=32;m;m>>=1){ s += __shfl_xor(s,m,64); sq += __shfl_xor(sq,m,64); }
  const int wv = tid>>6, lane = tid&63;
  if (lane==0){ red[wv]=s; red[4+wv]=sq; }
  __syncthreads();
  s  = red[0]+red[1]+red[2]+red[3];
  sq = red[4]+red[5]+red[6]+red[7];
  const float mean = s / (float)E_;
  const float var  = sq / (float)E_ - mean*mean;
  const float rs   = rsqrtf(var + 1e-6f);
  #pragma unroll
  for (int it=0; it<2; it++){
    const int c = tid*4 + it*1024;
    if (c < E_){
      const float4 v = vals[it];
      const float4 gw = *(const float4*)(lnw + c);
      const float4 bw = *(const float4*)(lnb + c);
      short4v o;
      o[0] = f2bf((v.x-mean)*rs*gw.x + bw.x);
      o[1] = f2bf((v.y-mean)*rs*gw.y + bw.y);
      o[2] = f2bf((v.z-mean)*rs*gw.z + bw.z);
      o[3] = f2bf((v.w-mean)*rs*gw.w + bw.w);
      *(short4v*)(aln + (long long)row*E_ + c) = o;
    }
  }
}

// ---------------- fused patch split-K(4) reduce + pos-embed add + ln1 ----------------
__global__ __launch_bounds__(256)
void redposln_k(const short* __restrict__ part, long long MN, const float* __restrict__ bias,
                const float* __restrict__ pe, float* __restrict__ h,
                const float* __restrict__ lnw, const float* __restrict__ lnb,
                short* __restrict__ aln)
{
  __shared__ float red[8];
  const int row = blockIdx.x, tid = threadIdx.x;
  const int t = row & 1023;
  int hc, wc; token_hw(t, hc, wc);
  const float hi = (float)hc * (47.f/31.f);
  const float wi = (float)wc * (47.f/31.f);
  int hf = (int)hi; float dh = hi - (float)hf; int h2 = min(hf+1, 47);
  int wf = (int)wi; float dw = wi - (float)wf; int w2 = min(wf+1, 47);
  const float w00=(1.f-dh)*(1.f-dw), w01=(1.f-dh)*dw, w10=dh*(1.f-dw), w11=dh*dw;
  const float* pe00 = pe + (long long)(hf*48+wf)*E_;
  const float* pe01 = pe + (long long)(hf*48+w2)*E_;
  const float* pe10 = pe + (long long)(h2*48+wf)*E_;
  const float* pe11 = pe + (long long)(h2*48+w2)*E_;

  float4 vals[2];
  float s = 0.f, sq = 0.f;
  #pragma unroll
  for (int it=0; it<2; it++){
    const int c = tid*4 + it*1024;
    if (c < E_){
      const float4 b = *(const float4*)(bias + c);
      const float4 a0 = *(const float4*)(pe00 + c);
      const float4 a1 = *(const float4*)(pe01 + c);
      const float4 a2 = *(const float4*)(pe10 + c);
      const float4 a3 = *(const float4*)(pe11 + c);
      float4 v;
      v.x = b.x + w00*a0.x + w01*a1.x + w10*a2.x + w11*a3.x;
      v.y = b.y + w00*a0.y + w01*a1.y + w10*a2.y + w11*a3.y;
      v.z = b.z + w00*a0.z + w01*a1.z + w10*a2.z + w11*a3.z;
      v.w = b.w + w00*a0.w + w01*a1.w + w10*a2.w + w11*a3.w;
      #pragma unroll
      for (int ks=0; ks<4; ks++){
        short4v pv = *(const short4v*)(part + (long long)ks*MN + (long long)row*E_ + c);
        v.x += bf2f(pv[0]); v.y += bf2f(pv[1]); v.z += bf2f(pv[2]); v.w += bf2f(pv[3]);
      }
      *(float4*)(h + (long long)row*E_ + c) = v;
      vals[it] = v;
      s  += v.x+v.y+v.z+v.w;
      sq += v.x*v.x+v.y*v.y+v.z*v.z+v.w*v.w;
    }
  }
  #pragma unroll
  for (int m=32;m;m>>=1){ s += __shfl_xor(s,m,64); sq += __shfl_xor(sq,m,64); }
  const int wv = tid>>6, lane = tid&63;
  if (lane==0){ red[wv]=s; red[4+wv]=sq; }
  __syncthreads();
  s  = red[0]+red[1]+red[2]+red[3];
  sq = red[4]+red[5]+red[6]+red[7];
  const float mean = s / (float)E_;
  const float var  = sq / (float)E_ - mean*mean;
  const float rs   = rsqrtf(var + 1e-6f);
  #pragma unroll
  for (int it=0; it<2; it++){
    const int c = tid*4 + it*1024;
    if (c < E_){
      const float4 v = vals[it];
      const float4 gw = *(const float4*)(lnw + c);
      const float4 bw = *(const float4*)(lnb + c);
      short4v o;
      o[0] = f2bf((v.x-mean)*rs*gw.x + bw.x);
      o[1] = f2bf((v.y-mean)*rs*gw.y + bw.y);
      o[2] = f2bf((v.z-mean)*rs*gw.z + bw.z);
      o[3] = f2bf((v.w-mean)*rs*gw.w + bw.w);
      *(short4v*)(aln + (long long)row*E_ + c) = o;
    }
  }
}

// ---------------- fused flash attention (L2-resident K/V; exp2-domain softmax) ------------
__global__ __launch_bounds__(256)
void fattn_k(const short* __restrict__ qh, const short* __restrict__ kh,
             const short* __restrict__ vt, short* __restrict__ o2)
{
  __shared__ short Ps[4][16*136];

  const int qt = blockIdx.x, h = blockIdx.y, img = blockIdx.z;
  const int tid = threadIdx.x, lane = tid & 63, wv = tid >> 6;
  const int fr = lane & 15, fo = (lane >> 4) * 8, g = lane >> 4;

  const short* qp = qh + ((long long)h*S_ + img*1024 + qt*64 + wv*16)*DP_;
  const short* kp = kh + ((long long)h*S_ + img*1024)*DP_;
  const short* vp = vt + ((long long)(h*2 + img))*80*1024;
  short* Pw = &Ps[wv][0];

  short8v q[3];
  #pragma unroll
  for (int t3=0;t3<3;t3++)
    q[t3] = *(const short8v*)(qp + (long long)fr*DP_ + t3*32 + fo);

  float m_[4], l_[4];
  f32x4 ao[5] = {};
  #pragma unroll
  for (int r=0;r<4;r++){ m_[r] = -3.0e38f; l_[r] = 0.f; }

  const float SC = 0.11180339887498949f * 1.4426950408889634f;

  for (int t = 0; t < 8; t++){
    f32x4 sc[8] = {};
    #pragma unroll
    for (int j=0;j<8;j++){
      #pragma unroll
      for (int t3=0;t3<3;t3++){
        const short8v kb = *(const short8v*)(kp + (long long)(t*128 + j*16 + fr)*DP_ + t3*32 + fo);
        sc[j] = __builtin_amdgcn_mfma_f32_16x16x32_bf16(q[t3], kb, sc[j], 0,0,0);
      }
    }
    #pragma unroll
    for (int j=0;j<8;j++) sc[j] *= SC;

    #pragma unroll
    for (int r=0;r<4;r++){
      float mx = sc[0][r];
      #pragma unroll
      for (int j=1;j<8;j++) mx = fmaxf(mx, sc[j][r]);
      mx = fmaxf(mx, __shfl_xor(mx, 1, 64));
      mx = fmaxf(mx, __shfl_xor(mx, 2, 64));
      mx = fmaxf(mx, __shfl_xor(mx, 4, 64));
      mx = fmaxf(mx, __shfl_xor(mx, 8, 64));
      const float mn = fmaxf(m_[r], mx);
      const float al = exp2f(m_[r] - mn);
      float ts = 0.f;
      #pragma unroll
      for (int j=0;j<8;j++){
        const float pv = exp2f(sc[j][r] - mn);
        sc[j][r] = pv;
        ts += pv;
      }
      ts += __shfl_xor(ts, 1, 64);
      ts += __shfl_xor(ts, 2, 64);
      ts += __shfl_xor(ts, 4, 64);
      ts += __shfl_xor(ts, 8, 64);
      l_[r] = l_[r]*al + ts;
      m_[r] = mn;
      #pragma unroll
      for (int n=0;n<5;n++) ao[n][r] *= al;
      const int prow = g*4 + r;
      #pragma unroll
      for (int j=0;j<8;j++) Pw[prow*136 + j*16 + fr] = f2bf(sc[j][r]);
    }
    asm volatile("s_waitcnt lgkmcnt(0)" ::: "memory");
    __builtin_amdgcn_sched_barrier(0);

    #pragma unroll
    for (int t4=0;t4<4;t4++){
      const short8v pa = *(const short8v*)&Pw[fr*136 + t4*32 + fo];
      #pragma unroll
      for (int n=0;n<5;n++){
        const short8v vb = *(const short8v*)(vp + (long long)(n*16 + fr)*1024 + t*128 + t4*32 + fo);
        ao[n] = __builtin_amdgcn_mfma_f32_16x16x32_bf16(pa, vb, ao[n], 0,0,0);
      }
    }
  }

  short* op = o2 + ((long long)(img*1024 + qt*64 + wv*16))*E_ + h*80;
  #pragma unroll
  for (int r=0;r<4;r++){
    const float inv = 1.f / l_[r];
    const int row = g*4 + r;
    #pragma unroll
    for (int n=0;n<5;n++)
      op[(long long)row*E_ + n*16 + fr] = f2bf(ao[n][r] * inv);
  }
}

// ---------------- LayerNorm (f32 in, bf16 out) ----------------
__global__ __launch_bounds__(256)
void ln_k(const float* __restrict__ X, const float* __restrict__ g, const float* __restrict__ bta,
          short* __restrict__ Y, int Cn)
{
  __shared__ float red[8];
  const int row = blockIdx.x;
  const float* x = X + (long long)row*Cn;
  short* y = Y + (long long)row*Cn;
  float s = 0.f, sq = 0.f;
  for (int c = threadIdx.x*4; c < Cn; c += 1024){
    float4 v = *(const float4*)(x + c);
    s  += v.x+v.y+v.z+v.w;
    sq += v.x*v.x+v.y*v.y+v.z*v.z+v.w*v.w;
  }
  #pragma unroll
  for (int m=32;m;m>>=1){ s += __shfl_xor(s,m,64); sq += __shfl_xor(sq,m,64); }
  const int wv = threadIdx.x>>6, lane = threadIdx.x&63;
  if (lane==0){ red[wv]=s; red[4+wv]=sq; }
  __syncthreads();
  s  = red[0]+red[1]+red[2]+red[3];
  sq = red[4]+red[5]+red[6]+red[7];
  const float mean = s / (float)Cn;
  const float var  = sq / (float)Cn - mean*mean;
  const float rs   = rsqrtf(var + 1e-6f);
  for (int c = threadIdx.x*4; c < Cn; c += 1024){
    float4 v  = *(const float4*)(x + c);
    float4 gw = *(const float4*)(g + c);
    float4 bw = *(const float4*)(bta + c);
    short4v o;
    o[0] = f2bf((v.x-mean)*rs*gw.x + bw.x);
    o[1] = f2bf((v.y-mean)*rs*gw.y + bw.y);
    o[2] = f2bf((v.z-mean)*rs*gw.z + bw.z);
    o[3] = f2bf((v.w-mean)*rs*gw.w + bw.w);
    *(short4v*)(y + c) = o;
  }
}

// ---------------- rope + head layout (bf16 qkv in) ----------------
__global__ __launch_bounds__(256)
void rope_k(const short* __restrict__ qkv, short* __restrict__ qh,
            short* __restrict__ kh, short* __restrict__ vt)
{
  const int idx = blockIdx.x*256 + threadIdx.x;
  if (idx >= S_*NH_*40) return;
  const int d0 = idx % 40;
  const int h  = (idx / 40) % NH_;
  const int s  = idx / (40*NH_);
  const int t  = s & 1023, img = s >> 10;
  int hc, wc; token_hw(t, hc, wc);
  const int j  = d0 % 20;
  const float invf = exp2f(-0.66438561897747f * (float)j);
  const float pos  = (float)((d0 < 20) ? hc : wc);
  float sn, cs;
  __sincosf(pos * invf, &sn, &cs);
  const short* base = qkv + (long long)s*3840 + h*80;
  const float q1 = bf2f(base[d0]),      q2 = bf2f(base[d0+40]);
  const float k1 = bf2f(base[1280+d0]), k2 = bf2f(base[1280+d0+40]);
  const long long qo = ((long long)h*S_ + s)*DP_;
  qh[qo + d0]    = f2bf(q1*cs - q2*sn);
  qh[qo + d0+40] = f2bf(q2*cs + q1*sn);
  kh[qo + d0]    = f2bf(k1*cs - k2*sn);
  kh[qo + d0+40] = f2bf(k2*cs + k1*sn);
  if (d0 < 16){ qh[qo + 80 + d0] = 0; kh[qo + 80 + d0] = 0; }
  const long long vo = (((long long)h*2 + img)*80)*1024 + t;
  vt[vo + (long long)d0*1024]      = base[2560+d0];
  vt[vo + (long long)(d0+40)*1024] = base[2560+d0+40];
}

// ---------------- host side ----------------
static Gemm2P mk(const short* A, const float* B, void* C, const float* bias,
                 int lda, int ldb, int ldc, int M, int N, int K)
{
  Gemm2P p{}; p.A=A; p.B=B; p.C=C; p.bias=bias; p.part=nullptr;
  p.lda=lda; p.ldb=ldb; p.ldc=ldc; p.M=M; p.N=N; p.K=K; p.scale=1.f; p.kSplit=1;
  return p;
}

extern "C" void kernel_launch(void* const* d_in, const int* in_sizes, int n_in,
                              void* d_out, int out_size, void* d_ws, size_t ws_size,
                              hipStream_t stream)
{
  const float* x           = (const float*)d_in[0];
  const float* patch_w     = (const float*)d_in[1];
  const float* patch_b     = (const float*)d_in[2];
  const float* pos_emb     = (const float*)d_in[3];
  const float* ln1_w       = (const float*)d_in[4];
  const float* ln1_b       = (const float*)d_in[5];
  const float* ln2_w       = (const float*)d_in[6];
  const float* ln2_b       = (const float*)d_in[7];
  const float* qkv_w       = (const float*)d_in[8];
  const float* qkv_b       = (const float*)d_in[9];
  const float* attn_proj_w = (const float*)d_in[10];
  const float* attn_proj_b = (const float*)d_in[11];
  const float* fc1_w       = (const float*)d_in[12];
  const float* fc1_b       = (const float*)d_in[13];
  const float* fc2_w       = (const float*)d_in[14];
  const float* fc2_b       = (const float*)d_in[15];
  const float* m_ln_w      = (const float*)d_in[16];
  const float* m_ln_b      = (const float*)d_in[17];
  const float* m_fc1_w     = (const float*)d_in[18];
  const float* m_fc1_b     = (const float*)d_in[19];
  const float* m_fc2_w     = (const float*)d_in[20];
  const float* m_fc2_b     = (const float*)d_in[21];
  const float* ds_ln_w     = (const float*)d_in[22];
  const float* ds_ln_b     = (const float*)d_in[23];
  const float* ds_fc1_w    = (const float*)d_in[24];
  const float* ds_fc1_b    = (const float*)d_in[25];
  const float* ds_fc2_w    = (const float*)d_in[26];
  const float* ds_fc2_b    = (const float*)d_in[27];
  float* out = (float*)d_out;

  char* wsp = (char*)d_ws;
  auto alloc = [&](size_t bytes)->char*{
    char* p = wsp; wsp += (bytes + 255) & ~(size_t)255; return p;
  };
  float* h    = (float*)alloc((size_t)S_*E_*4);
  short* qkvb = (short*)alloc((size_t)S_*3840*2);
  short* aln  = (short*)alloc((size_t)S_*E_*2);
  short* qh   = (short*)alloc((size_t)NH_*S_*DP_*2);
  short* kh   = (short*)alloc((size_t)NH_*S_*DP_*2 + 4096);
  short* vt   = (short*)alloc((size_t)NH_*2*D_*1024*2 + 4096);
  short* part = (short*)alloc((size_t)48*1024*1024);
  short* o2   = (short*)alloc((size_t)S_*E_*2);
  short* ffn  = (short*)alloc((size_t)S_*MLP_*2);
  short* xb   = (short*)alloc((size_t)S_*INP_*2);
  size_t need = (size_t)(wsp - (char*)d_ws);
  if (need > ws_size){
    fprintf(stderr, "kernel_launch: ws too small: need %zu have %zu\n", need, ws_size);
    return;
  }
  short* dsln = qkvb;   // ds-merger LN output (512x5120) aliases qkvb (free then)

  const dim3 B256(256);
  // only x still needs a bulk convert (weights are consumed f32 by the GEMM directly)
  { long long n = (long long)S_*INP_;
    unsigned blk = (unsigned)min((long long)8192, (n/8 + 255)/256);
    cvt_k<<<blk, B256, 0, stream>>>(x, xb, n); }

  auto G = [](int M, int N, int ks = 1){
    return dim3((unsigned)((N+127)/128), (unsigned)((M+127)/128), (unsigned)ks);
  };
  auto RG = [](long long MN){ return dim3((unsigned)((MN/8 + 255)/256)); };

  // patch embed split-K x4, fused reduce + pos-embed + ln1(layer0)
  { Gemm2P pp = mk(xb, patch_w, nullptr, nullptr, INP_, INP_, E_, S_, E_, INP_);
    pp.part = part; pp.kSplit = 4;
    gemm2_k<0,false,true,true><<<G(S_,E_,4),B256,0,stream>>>(pp);
    redposln_k<<<S_, B256, 0, stream>>>(part, (long long)S_*E_, patch_b, pos_emb,
                                        h, ln1_w, ln1_b, aln); }

  for (int l = 0; l < L_; l++){
    // qkv: direct epilogue (480 blocks)
    { Gemm2P pp = mk(aln, qkv_w + (size_t)l*3840*E_, qkvb, qkv_b + l*3840, E_, E_, 3840, S_, 3840, E_);
      gemm2_k<0,false,false,false><<<G(S_,3840),B256,0,stream>>>(pp); }
    rope_k<<<(S_*NH_*40+255)/256, B256, 0, stream>>>(qkvb, qh, kh, vt);
    fattn_k<<<dim3(16,16,2), B256, 0, stream>>>(qh, kh, vt, o2);
    // attn proj split-K x4, fused reduce+residual+ln2
    { Gemm2P pp = mk(o2, attn_proj_w + (size_t)l*E_*E_, nullptr, nullptr, E_, E_, E_, S_, E_, E_);
      pp.part = part; pp.kSplit = 4;
      gemm2_k<0,false,true,true><<<G(S_,E_,4),B256,0,stream>>>(pp);
      redln_k<<<S_, B256, 0, stream>>>(part, (long long)S_*E_, attn_proj_b + l*E_,
                                       h, ln2_w + l*E_, ln2_b + l*E_, aln); }

    // MLP: fc1 direct epilogue (gelu in epilogue, 640 blocks)
    { Gemm2P pp = mk(aln, fc1_w + (size_t)l*MLP_*E_, ffn, fc1_b + l*MLP_, E_, E_, MLP_, S_, MLP_, E_);
      gemm2_k<1,false,false,false><<<G(S_,MLP_),B256,0,stream>>>(pp); }
    // fc2 split-K x4, fused reduce+residual+(next ln1 | m_ln)
    { Gemm2P pp = mk(ffn, fc2_w + (size_t)l*E_*MLP_, nullptr, nullptr, MLP_, MLP_, E_, S_, E_, MLP_);
      pp.part = part; pp.kSplit = 4;
      gemm2_k<0,false,true,true><<<G(S_,E_,4),B256,0,stream>>>(pp);
      const float* nw = (l < 3) ? (ln1_w + (l+1)*E_) : m_ln_w;
      const float* nb = (l < 3) ? (ln1_b + (l+1)*E_) : m_ln_b;
      redln_k<<<S_, B256, 0, stream>>>(part, (long long)S_*E_, fc2_b + l*E_, h, nw, nb, aln); }

    // deepstack mergers after layers 1 and 2
    if (l == 1 || l == 2){
      const int j = l - 1;
      ln_k<<<512, B256, 0, stream>>>(h, ds_ln_w + (size_t)j*H4_, ds_ln_b + (size_t)j*H4_, dsln, H4_);
      { Gemm2P pp = mk(dsln, ds_fc1_w + (size_t)j*H4_*H4_, ffn, nullptr, H4_, H4_, H4_, 512, H4_, H4_);
        pp.part = part; pp.kSplit = 4;
        gemm2_k<0,false,false,true><<<G(512,H4_,4),B256,0,stream>>>(pp);
        reduce_k<2,false,false><<<RG((long long)512*H4_),B256,0,stream>>>(part, 4, (long long)512*H4_, H4_, ds_fc1_b + (size_t)j*H4_, ffn); }
      { Gemm2P pp = mk(ffn, ds_fc2_w + (size_t)j*O_*H4_, out + (size_t)(1+j)*512*O_, nullptr, H4_, H4_, O_, 512, O_, H4_);
        pp.part = part; pp.kSplit = 8;
        gemm2_k<0,false,true,true><<<G(512,O_,8),B256,0,stream>>>(pp);
        reduce_k<0,false,true><<<RG((long long)512*O_),B256,0,stream>>>(part, 8, (long long)512*O_, O_, ds_fc2_b + (size_t)j*O_, out + (size_t)(1+j)*512*O_); }
    }
  }

  // main merger (aln holds m_ln(h) from the last fc2-redln)
  { Gemm2P pp = mk(aln, m_fc1_w, ffn, nullptr, H4_, H4_, H4_, 512, H4_, H4_);
    pp.part = part; pp.kSplit = 4;
    gemm2_k<0,false,false,true><<<G(512,H4_,4),B256,0,stream>>>(pp);
    reduce_k<2,false,false><<<RG((long long)512*H4_),B256,0,stream>>>(part, 4, (long long)512*H4_, H4_, m_fc1_b, ffn); }
  { Gemm2P pp = mk(ffn, m_fc2_w, out, nullptr, H4_, H4_, O_, 512, O_, H4_);
    pp.part = part; pp.kSplit = 8;
    gemm2_k<0,false,true,true><<<G(512,O_,8),B256,0,stream>>>(pp);
    reduce_k<0,false,true><<<RG((long long)512*O_),B256,0,stream>>>(part, 8, (long long)512*O_, O_, m_fc2_b, out); }
}

// Round 12
// 1646.469 us; speedup vs baseline: 1.0707x; 1.0707x over previous
//
#include <hip/hip_runtime.h>
#include <hip/hip_bf16.h>
#include <cstdio>
#include <cstdint>

// ---------------- model dims ----------------
#define E_    1280
#define L_    4
#define NH_   16
#define D_    80
#define DP_   96      // D padded to mult of 32 for QK^T K-loop
#define MLP_  5120
#define O_    2048
#define S_    2048
#define H4_   5120
#define INP_  1536

typedef __attribute__((ext_vector_type(4))) float f32x4;
typedef __attribute__((ext_vector_type(8))) short short8v;
typedef __attribute__((ext_vector_type(4))) short short4v;

__device__ __forceinline__ short f2bf(float f){
  uint32_t u = __float_as_uint(f);
  uint32_t r = (u + 0x7FFFu + ((u >> 16) & 1u)) >> 16;   // RNE
  return (short)r;
}
__device__ __forceinline__ float bf2f(short s){
  return __uint_as_float(((uint32_t)(uint16_t)s) << 16);
}
__device__ __forceinline__ float gelu_tanh(float x){
  const float z = 0.7978845608028654f*(x + 0.044715f*x*x*x);
  const float e = __expf(2.f*z);
  return 0.5f*x*(1.f + (e-1.f)/(e+1.f));
}
__device__ __forceinline__ float gelu_erf(float x){
  return 0.5f*x*(1.f + erff(x*0.7071067811865476f));
}
__device__ __forceinline__ void token_hw(int t, int& hc, int& wc){
  hc = ((t>>1)&1) + ((t>>6)<<1);
  wc = (t&1)      + (((t>>2)&15)<<1);
}
__device__ __forceinline__ void gload16(const short* g, short* l){
  __builtin_amdgcn_global_load_lds((const __attribute__((address_space(1))) void*)g,
                                   (__attribute__((address_space(3))) void*)l, 16, 0, 0);
}

// ---------------- f32 -> bf16 bulk convert ----------------
__global__ __launch_bounds__(256)
void cvt_k(const float* __restrict__ src, short* __restrict__ dst, long long n)
{
  const long long stride = (long long)gridDim.x*256*8;
  for (long long i = ((long long)blockIdx.x*256 + threadIdx.x)*8; i < n; i += stride){
    float4 v0 = *(const float4*)(src+i);
    float4 v1 = *(const float4*)(src+i+4);
    short8v w;
    w[0]=f2bf(v0.x); w[1]=f2bf(v0.y); w[2]=f2bf(v0.z); w[3]=f2bf(v0.w);
    w[4]=f2bf(v1.x); w[5]=f2bf(v1.y); w[6]=f2bf(v1.z); w[7]=f2bf(v1.w);
    *(short8v*)(dst+i) = w;
  }
}

// ---------------- GEMM: bf16, 3-buffer ring, counted vmcnt, chunk-swizzled LDS ----------
// C[m][n] = epi( sum_k A[m][k]*B[n][k] + bias[n] ) (+ residual from C)
// A:(M,K) bf16 row-major, B:(N,K) bf16 row-major.
// Requires M%128==0, N%128==0, (K/kSplit)%32==0 (all call sites satisfy this).
// LDS 8KB tile = 512 x 16B chunks; swizzle sigma(c)=c^((c>>3)&7) (involution):
// linear global_load_lds dest, inverse-permuted GLOBAL source, sigma-indexed ds_read.
struct Gemm2P {
  const short* A; const short* B; void* C;
  const float* bias;
  short* part;                  // split-K partial buffer [kSplit][M][N] bf16
  int lda, ldb, ldc, M, N, K;
  float scale;
  long long aOffH, aOffI, bOffH, bOffI, cOffH, cOffI;
  int nImg, kSplit;
};

template<int EPI, bool RES, bool CF32, bool SPLIT>   // EPI: 0=none,1=gelu_tanh,2=gelu_erf,3=scale
__global__ __launch_bounds__(256)
void gemm2_k(Gemm2P p)
{
  __shared__ short As[3][4096];   // [buf][512 chunks x 8 shorts]
  __shared__ short Bs[3][4096];

  int z = blockIdx.z, ks = 0;
  if constexpr (SPLIT){ ks = z % p.kSplit; z /= p.kSplit; }
  const int hI = z / p.nImg, iI = z % p.nImg;
  const long long aB = (long long)hI*p.aOffH + (long long)iI*p.aOffI;
  const long long bB = (long long)hI*p.bOffH + (long long)iI*p.bOffI;
  const long long cB = (long long)hI*p.cOffH + (long long)iI*p.cOffI;

  // bijective XCD swizzle on the tile plane (m204)
  const int nwg = gridDim.x*gridDim.y;
  const int orig = blockIdx.y*gridDim.x + blockIdx.x;
  const int q8 = nwg >> 3, r8 = nwg & 7;
  const int xcd = orig & 7, oidx = orig >> 3;
  const int wg = (xcd < r8 ? xcd*(q8+1) : r8*(q8+1) + (xcd-r8)*q8) + oidx;
  const int nt = wg % gridDim.x, mt = wg / gridDim.x;

  const int tid = threadIdx.x, lane = tid & 63, wv = tid >> 6;

  // staging: wave wv fills segments (wv*2, wv*2+1); LDS dest linear (lane*16B).
  const int lam = lane ^ ((lane >> 3) & 7);
  const int sr = lam >> 2;              // row within the segment's 16 rows
  const int sc = (lam & 3) * 8;         // col in shorts
  const int Kp  = SPLIT ? p.K / p.kSplit : p.K;
  const int kBeg = SPLIT ? ks * Kp : 0;
  const short* pa0 = p.A + aB + (long long)(mt*128 + (wv*2+0)*16 + sr)*p.lda + sc + kBeg;
  const short* pa1 = p.A + aB + (long long)(mt*128 + (wv*2+1)*16 + sr)*p.lda + sc + kBeg;
  const short* pb0 = p.B + bB + (long long)(nt*128 + (wv*2+0)*16 + sr)*p.ldb + sc + kBeg;
  const short* pb1 = p.B + bB + (long long)(nt*128 + (wv*2+1)*16 + sr)*p.ldb + sc + kBeg;
  const int so0 = (wv*2+0)*512;
  const int so1 = (wv*2+1)*512;

  const int fr = lane & 15, g4 = lane >> 4;
  const int wr = (wv >> 1) * 64, wc = (wv & 1) * 64;

  f32x4 acc[4][4] = {};

  auto stage = [&](int buf, int t){
    const int k0 = t << 5;
    gload16(pa0 + k0, &As[buf][so0]);
    gload16(pa1 + k0, &As[buf][so1]);
    gload16(pb0 + k0, &Bs[buf][so0]);
    gload16(pb1 + k0, &Bs[buf][so1]);
  };

  const int ntile = Kp >> 5;
  stage(0, 0);
  if (ntile > 1) stage(1, 1);
  for (int t = 0; t < ntile; t++){
    const int cur = t % 3;
    if (t + 1 < ntile) { asm volatile("s_waitcnt vmcnt(4)" ::: "memory"); }
    else               { asm volatile("s_waitcnt vmcnt(0)" ::: "memory"); }
    __builtin_amdgcn_s_barrier();
    asm volatile("" ::: "memory");
    short8v a[4], b[4];
    #pragma unroll
    for (int i=0;i<4;i++){
      const int ra = wr + i*16 + fr;
      const int ca = (ra*4 + g4) ^ ((ra>>1)&7);     // sigma-indexed chunk
      a[i] = *(const short8v*)&As[cur][ca*8];
      const int rb = wc + i*16 + fr;
      const int cb = (rb*4 + g4) ^ ((rb>>1)&7);
      b[i] = *(const short8v*)&Bs[cur][cb*8];
    }
    if (t + 2 < ntile) stage((t+2)%3, t+2);   // buf last read at t-1; all waves past barrier(t)
    #pragma unroll
    for (int i=0;i<4;i++)
      #pragma unroll
      for (int j=0;j<4;j++)
        acc[i][j] = __builtin_amdgcn_mfma_f32_16x16x32_bf16(a[i], b[j], acc[i][j], 0, 0, 0);
  }

  #pragma unroll
  for (int i=0;i<4;i++){
    #pragma unroll
    for (int j=0;j<4;j++){
      #pragma unroll
      for (int r=0;r<4;r++){
        const int row = mt*128 + wr + i*16 + g4*4 + r;
        const int col = nt*128 + wc + j*16 + fr;
        float v = acc[i][j][r];
        if constexpr (SPLIT){
          p.part[((long long)ks*p.M + row)*p.N + col] = f2bf(v);
        } else {
          if (p.bias) v += p.bias[col];
          if constexpr (EPI==1) v = gelu_tanh(v);
          if constexpr (EPI==2) v = gelu_erf(v);
          if constexpr (EPI==3) v *= p.scale;
          const long long off = cB + (long long)row*p.ldc + col;
          if constexpr (RES)  v += ((const float*)p.C)[off];
          if constexpr (CF32) ((float*)p.C)[off] = v;
          else                ((short*)p.C)[off] = f2bf(v);
        }
      }
    }
  }
}

// ---------------- split-K reduce (C contiguous, ldc == N), bf16 partials ----------------
template<int EPI, bool RES, bool CF32>
__global__ __launch_bounds__(256)
void reduce_k(const short* __restrict__ part, int kSplit, long long MN, int N,
              const float* __restrict__ bias, void* __restrict__ C)
{
  const long long i = ((long long)blockIdx.x*256 + threadIdx.x)*8;
  if (i >= MN) return;
  float v[8];
  { short8v pv = *(const short8v*)(part + i);
    #pragma unroll
    for (int e=0;e<8;e++) v[e] = bf2f(pv[e]); }
  for (int ks = 1; ks < kSplit; ks++){
    short8v pv = *(const short8v*)(part + (long long)ks*MN + i);
    #pragma unroll
    for (int e=0;e<8;e++) v[e] += bf2f(pv[e]);
  }
  if (bias){
    const int col = (int)(i % N);
    #pragma unroll
    for (int e=0;e<8;e++) v[e] += bias[col+e];
  }
  #pragma unroll
  for (int e=0;e<8;e++){
    if constexpr (EPI==1) v[e] = gelu_tanh(v[e]);
    if constexpr (EPI==2) v[e] = gelu_erf(v[e]);
  }
  if constexpr (RES){
    const float* cp = (const float*)C + i;
    #pragma unroll
    for (int e=0;e<8;e++) v[e] += cp[e];
  }
  if constexpr (CF32){
    float4 o0 = {v[0],v[1],v[2],v[3]}, o1 = {v[4],v[5],v[6],v[7]};
    *(float4*)((float*)C + i) = o0;
    *(float4*)((float*)C + i + 4) = o1;
  } else {
    short8v o;
    #pragma unroll
    for (int e=0;e<8;e++) o[e] = f2bf(v[e]);
    *(short8v*)((short*)C + i) = o;
  }
}

// ---------------- fused split-K(4) reduce + residual + LayerNorm (rows of E) ----------------
__global__ __launch_bounds__(256)
void redln_k(const short* __restrict__ part, long long MN, const float* __restrict__ bias,
             float* __restrict__ h, const float* __restrict__ lnw, const float* __restrict__ lnb,
             short* __restrict__ aln)
{
  __shared__ float red[8];
  const int row = blockIdx.x, tid = threadIdx.x;
  float4 vals[2];
  float s = 0.f, sq = 0.f;
  #pragma unroll
  for (int it=0; it<2; it++){
    const int c = tid*4 + it*1024;
    if (c < E_){
      float4 v = *(const float4*)(h + (long long)row*E_ + c);
      const float4 b = *(const float4*)(bias + c);
      v.x += b.x; v.y += b.y; v.z += b.z; v.w += b.w;
      #pragma unroll
      for (int ks=0; ks<4; ks++){
        short4v pv = *(const short4v*)(part + (long long)ks*MN + (long long)row*E_ + c);
        v.x += bf2f(pv[0]); v.y += bf2f(pv[1]); v.z += bf2f(pv[2]); v.w += bf2f(pv[3]);
      }
      *(float4*)(h + (long long)row*E_ + c) = v;
      vals[it] = v;
      s  += v.x+v.y+v.z+v.w;
      sq += v.x*v.x+v.y*v.y+v.z*v.z+v.w*v.w;
    }
  }
  #pragma unroll
  for (int m=32;m;m>>=1){ s += __shfl_xor(s,m,64); sq += __shfl_xor(sq,m,64); }
  const int wv = tid>>6, lane = tid&63;
  if (lane==0){ red[wv]=s; red[4+wv]=sq; }
  __syncthreads();
  s  = red[0]+red[1]+red[2]+red[3];
  sq = red[4]+red[5]+red[6]+red[7];
  const float mean = s / (float)E_;
  const float var  = sq / (float)E_ - mean*mean;
  const float rs   = rsqrtf(var + 1e-6f);
  #pragma unroll
  for (int it=0; it<2; it++){
    const int c = tid*4 + it*1024;
    if (c < E_){
      const float4 v = vals[it];
      const float4 gw = *(const float4*)(lnw + c);
      const float4 bw = *(const float4*)(lnb + c);
      short4v o;
      o[0] = f2bf((v.x-mean)*rs*gw.x + bw.x);
      o[1] = f2bf((v.y-mean)*rs*gw.y + bw.y);
      o[2] = f2bf((v.z-mean)*rs*gw.z + bw.z);
      o[3] = f2bf((v.w-mean)*rs*gw.w + bw.w);
      *(short4v*)(aln + (long long)row*E_ + c) = o;
    }
  }
}

// ---------------- fused patch split-K(4) reduce + pos-embed add + ln1 ----------------
__global__ __launch_bounds__(256)
void redposln_k(const short* __restrict__ part, long long MN, const float* __restrict__ bias,
                const float* __restrict__ pe, float* __restrict__ h,
                const float* __restrict__ lnw, const float* __restrict__ lnb,
                short* __restrict__ aln)
{
  __shared__ float red[8];
  const int row = blockIdx.x, tid = threadIdx.x;
  const int t = row & 1023;
  int hc, wc; token_hw(t, hc, wc);
  const float hi = (float)hc * (47.f/31.f);
  const float wi = (float)wc * (47.f/31.f);
  int hf = (int)hi; float dh = hi - (float)hf; int h2 = min(hf+1, 47);
  int wf = (int)wi; float dw = wi - (float)wf; int w2 = min(wf+1, 47);
  const float w00=(1.f-dh)*(1.f-dw), w01=(1.f-dh)*dw, w10=dh*(1.f-dw), w11=dh*dw;
  const float* pe00 = pe + (long long)(hf*48+wf)*E_;
  const float* pe01 = pe + (long long)(hf*48+w2)*E_;
  const float* pe10 = pe + (long long)(h2*48+wf)*E_;
  const float* pe11 = pe + (long long)(h2*48+w2)*E_;

  float4 vals[2];
  float s = 0.f, sq = 0.f;
  #pragma unroll
  for (int it=0; it<2; it++){
    const int c = tid*4 + it*1024;
    if (c < E_){
      const float4 b = *(const float4*)(bias + c);
      const float4 a0 = *(const float4*)(pe00 + c);
      const float4 a1 = *(const float4*)(pe01 + c);
      const float4 a2 = *(const float4*)(pe10 + c);
      const float4 a3 = *(const float4*)(pe11 + c);
      float4 v;
      v.x = b.x + w00*a0.x + w01*a1.x + w10*a2.x + w11*a3.x;
      v.y = b.y + w00*a0.y + w01*a1.y + w10*a2.y + w11*a3.y;
      v.z = b.z + w00*a0.z + w01*a1.z + w10*a2.z + w11*a3.z;
      v.w = b.w + w00*a0.w + w01*a1.w + w10*a2.w + w11*a3.w;
      #pragma unroll
      for (int ks=0; ks<4; ks++){
        short4v pv = *(const short4v*)(part + (long long)ks*MN + (long long)row*E_ + c);
        v.x += bf2f(pv[0]); v.y += bf2f(pv[1]); v.z += bf2f(pv[2]); v.w += bf2f(pv[3]);
      }
      *(float4*)(h + (long long)row*E_ + c) = v;
      vals[it] = v;
      s  += v.x+v.y+v.z+v.w;
      sq += v.x*v.x+v.y*v.y+v.z*v.z+v.w*v.w;
    }
  }
  #pragma unroll
  for (int m=32;m;m>>=1){ s += __shfl_xor(s,m,64); sq += __shfl_xor(sq,m,64); }
  const int wv = tid>>6, lane = tid&63;
  if (lane==0){ red[wv]=s; red[4+wv]=sq; }
  __syncthreads();
  s  = red[0]+red[1]+red[2]+red[3];
  sq = red[4]+red[5]+red[6]+red[7];
  const float mean = s / (float)E_;
  const float var  = sq / (float)E_ - mean*mean;
  const float rs   = rsqrtf(var + 1e-6f);
  #pragma unroll
  for (int it=0; it<2; it++){
    const int c = tid*4 + it*1024;
    if (c < E_){
      const float4 v = vals[it];
      const float4 gw = *(const float4*)(lnw + c);
      const float4 bw = *(const float4*)(lnb + c);
      short4v o;
      o[0] = f2bf((v.x-mean)*rs*gw.x + bw.x);
      o[1] = f2bf((v.y-mean)*rs*gw.y + bw.y);
      o[2] = f2bf((v.z-mean)*rs*gw.z + bw.z);
      o[3] = f2bf((v.w-mean)*rs*gw.w + bw.w);
      *(short4v*)(aln + (long long)row*E_ + c) = o;
    }
  }
}

// ---------------- fused flash attention (L2-resident K/V; exp2-domain softmax) ------------
__global__ __launch_bounds__(256)
void fattn_k(const short* __restrict__ qh, const short* __restrict__ kh,
             const short* __restrict__ vt, short* __restrict__ o2)
{
  __shared__ short Ps[4][16*136];

  const int qt = blockIdx.x, h = blockIdx.y, img = blockIdx.z;
  const int tid = threadIdx.x, lane = tid & 63, wv = tid >> 6;
  const int fr = lane & 15, fo = (lane >> 4) * 8, g = lane >> 4;

  const short* qp = qh + ((long long)h*S_ + img*1024 + qt*64 + wv*16)*DP_;
  const short* kp = kh + ((long long)h*S_ + img*1024)*DP_;
  const short* vp = vt + ((long long)(h*2 + img))*80*1024;
  short* Pw = &Ps[wv][0];

  short8v q[3];
  #pragma unroll
  for (int t3=0;t3<3;t3++)
    q[t3] = *(const short8v*)(qp + (long long)fr*DP_ + t3*32 + fo);

  float m_[4], l_[4];
  f32x4 ao[5] = {};
  #pragma unroll
  for (int r=0;r<4;r++){ m_[r] = -3.0e38f; l_[r] = 0.f; }

  const float SC = 0.11180339887498949f * 1.4426950408889634f;

  for (int t = 0; t < 8; t++){
    f32x4 sc[8] = {};
    #pragma unroll
    for (int j=0;j<8;j++){
      #pragma unroll
      for (int t3=0;t3<3;t3++){
        const short8v kb = *(const short8v*)(kp + (long long)(t*128 + j*16 + fr)*DP_ + t3*32 + fo);
        sc[j] = __builtin_amdgcn_mfma_f32_16x16x32_bf16(q[t3], kb, sc[j], 0,0,0);
      }
    }
    #pragma unroll
    for (int j=0;j<8;j++) sc[j] *= SC;

    #pragma unroll
    for (int r=0;r<4;r++){
      float mx = sc[0][r];
      #pragma unroll
      for (int j=1;j<8;j++) mx = fmaxf(mx, sc[j][r]);
      mx = fmaxf(mx, __shfl_xor(mx, 1, 64));
      mx = fmaxf(mx, __shfl_xor(mx, 2, 64));
      mx = fmaxf(mx, __shfl_xor(mx, 4, 64));
      mx = fmaxf(mx, __shfl_xor(mx, 8, 64));
      const float mn = fmaxf(m_[r], mx);
      const float al = exp2f(m_[r] - mn);
      float ts = 0.f;
      #pragma unroll
      for (int j=0;j<8;j++){
        const float pv = exp2f(sc[j][r] - mn);
        sc[j][r] = pv;
        ts += pv;
      }
      ts += __shfl_xor(ts, 1, 64);
      ts += __shfl_xor(ts, 2, 64);
      ts += __shfl_xor(ts, 4, 64);
      ts += __shfl_xor(ts, 8, 64);
      l_[r] = l_[r]*al + ts;
      m_[r] = mn;
      #pragma unroll
      for (int n=0;n<5;n++) ao[n][r] *= al;
      const int prow = g*4 + r;
      #pragma unroll
      for (int j=0;j<8;j++) Pw[prow*136 + j*16 + fr] = f2bf(sc[j][r]);
    }
    asm volatile("s_waitcnt lgkmcnt(0)" ::: "memory");
    __builtin_amdgcn_sched_barrier(0);

    #pragma unroll
    for (int t4=0;t4<4;t4++){
      const short8v pa = *(const short8v*)&Pw[fr*136 + t4*32 + fo];
      #pragma unroll
      for (int n=0;n<5;n++){
        const short8v vb = *(const short8v*)(vp + (long long)(n*16 + fr)*1024 + t*128 + t4*32 + fo);
        ao[n] = __builtin_amdgcn_mfma_f32_16x16x32_bf16(pa, vb, ao[n], 0,0,0);
      }
    }
  }

  short* op = o2 + ((long long)(img*1024 + qt*64 + wv*16))*E_ + h*80;
  #pragma unroll
  for (int r=0;r<4;r++){
    const float inv = 1.f / l_[r];
    const int row = g*4 + r;
    #pragma unroll
    for (int n=0;n<5;n++)
      op[(long long)row*E_ + n*16 + fr] = f2bf(ao[n][r] * inv);
  }
}

// ---------------- LayerNorm (f32 in, bf16 out) ----------------
__global__ __launch_bounds__(256)
void ln_k(const float* __restrict__ X, const float* __restrict__ g, const float* __restrict__ bta,
          short* __restrict__ Y, int Cn)
{
  __shared__ float red[8];
  const int row = blockIdx.x;
  const float* x = X + (long long)row*Cn;
  short* y = Y + (long long)row*Cn;
  float s = 0.f, sq = 0.f;
  for (int c = threadIdx.x*4; c < Cn; c += 1024){
    float4 v = *(const float4*)(x + c);
    s  += v.x+v.y+v.z+v.w;
    sq += v.x*v.x+v.y*v.y+v.z*v.z+v.w*v.w;
  }
  #pragma unroll
  for (int m=32;m;m>>=1){ s += __shfl_xor(s,m,64); sq += __shfl_xor(sq,m,64); }
  const int wv = threadIdx.x>>6, lane = threadIdx.x&63;
  if (lane==0){ red[wv]=s; red[4+wv]=sq; }
  __syncthreads();
  s  = red[0]+red[1]+red[2]+red[3];
  sq = red[4]+red[5]+red[6]+red[7];
  const float mean = s / (float)Cn;
  const float var  = sq / (float)Cn - mean*mean;
  const float rs   = rsqrtf(var + 1e-6f);
  for (int c = threadIdx.x*4; c < Cn; c += 1024){
    float4 v  = *(const float4*)(x + c);
    float4 gw = *(const float4*)(g + c);
    float4 bw = *(const float4*)(bta + c);
    short4v o;
    o[0] = f2bf((v.x-mean)*rs*gw.x + bw.x);
    o[1] = f2bf((v.y-mean)*rs*gw.y + bw.y);
    o[2] = f2bf((v.z-mean)*rs*gw.z + bw.z);
    o[3] = f2bf((v.w-mean)*rs*gw.w + bw.w);
    *(short4v*)(y + c) = o;
  }
}

// ---------------- rope + head layout (bf16 qkv in) ----------------
__global__ __launch_bounds__(256)
void rope_k(const short* __restrict__ qkv, short* __restrict__ qh,
            short* __restrict__ kh, short* __restrict__ vt)
{
  const int idx = blockIdx.x*256 + threadIdx.x;
  if (idx >= S_*NH_*40) return;
  const int d0 = idx % 40;
  const int h  = (idx / 40) % NH_;
  const int s  = idx / (40*NH_);
  const int t  = s & 1023, img = s >> 10;
  int hc, wc; token_hw(t, hc, wc);
  const int j  = d0 % 20;
  const float invf = exp2f(-0.66438561897747f * (float)j);
  const float pos  = (float)((d0 < 20) ? hc : wc);
  float sn, cs;
  __sincosf(pos * invf, &sn, &cs);
  const short* base = qkv + (long long)s*3840 + h*80;
  const float q1 = bf2f(base[d0]),      q2 = bf2f(base[d0+40]);
  const float k1 = bf2f(base[1280+d0]), k2 = bf2f(base[1280+d0+40]);
  const long long qo = ((long long)h*S_ + s)*DP_;
  qh[qo + d0]    = f2bf(q1*cs - q2*sn);
  qh[qo + d0+40] = f2bf(q2*cs + q1*sn);
  kh[qo + d0]    = f2bf(k1*cs - k2*sn);
  kh[qo + d0+40] = f2bf(k2*cs + k1*sn);
  if (d0 < 16){ qh[qo + 80 + d0] = 0; kh[qo + 80 + d0] = 0; }
  const long long vo = (((long long)h*2 + img)*80)*1024 + t;
  vt[vo + (long long)d0*1024]      = base[2560+d0];
  vt[vo + (long long)(d0+40)*1024] = base[2560+d0+40];
}

// ---------------- host side ----------------
static Gemm2P mk(const short* A, const short* B, void* C, const float* bias,
                 int lda, int ldb, int ldc, int M, int N, int K, float scale = 1.f)
{
  Gemm2P p{}; p.A=A; p.B=B; p.C=C; p.bias=bias; p.part=nullptr;
  p.lda=lda; p.ldb=ldb; p.ldc=ldc; p.M=M; p.N=N; p.K=K; p.scale=scale;
  p.aOffH=p.aOffI=p.bOffH=p.bOffI=p.cOffH=p.cOffI=0; p.nImg=1; p.kSplit=1;
  return p;
}

extern "C" void kernel_launch(void* const* d_in, const int* in_sizes, int n_in,
                              void* d_out, int out_size, void* d_ws, size_t ws_size,
                              hipStream_t stream)
{
  const float* x           = (const float*)d_in[0];
  const float* patch_w     = (const float*)d_in[1];
  const float* patch_b     = (const float*)d_in[2];
  const float* pos_emb     = (const float*)d_in[3];
  const float* ln1_w       = (const float*)d_in[4];
  const float* ln1_b       = (const float*)d_in[5];
  const float* ln2_w       = (const float*)d_in[6];
  const float* ln2_b       = (const float*)d_in[7];
  const float* qkv_w       = (const float*)d_in[8];
  const float* qkv_b       = (const float*)d_in[9];
  const float* attn_proj_w = (const float*)d_in[10];
  const float* attn_proj_b = (const float*)d_in[11];
  const float* fc1_w       = (const float*)d_in[12];
  const float* fc1_b       = (const float*)d_in[13];
  const float* fc2_w       = (const float*)d_in[14];
  const float* fc2_b       = (const float*)d_in[15];
  const float* m_ln_w      = (const float*)d_in[16];
  const float* m_ln_b      = (const float*)d_in[17];
  const float* m_fc1_w     = (const float*)d_in[18];
  const float* m_fc1_b     = (const float*)d_in[19];
  const float* m_fc2_w     = (const float*)d_in[20];
  const float* m_fc2_b     = (const float*)d_in[21];
  const float* ds_ln_w     = (const float*)d_in[22];
  const float* ds_ln_b     = (const float*)d_in[23];
  const float* ds_fc1_w    = (const float*)d_in[24];
  const float* ds_fc1_b    = (const float*)d_in[25];
  const float* ds_fc2_w    = (const float*)d_in[26];
  const float* ds_fc2_b    = (const float*)d_in[27];
  float* out = (float*)d_out;

  char* wsp = (char*)d_ws;
  auto alloc = [&](size_t bytes)->char*{
    char* p = wsp; wsp += (bytes + 255) & ~(size_t)255; return p;
  };
  float* h    = (float*)alloc((size_t)S_*E_*4);
  short* qkvb = (short*)alloc((size_t)S_*3840*2);
  short* aln  = (short*)alloc((size_t)S_*E_*2);
  short* qh   = (short*)alloc((size_t)NH_*S_*DP_*2);
  short* kh   = (short*)alloc((size_t)NH_*S_*DP_*2 + 4096);
  short* vt   = (short*)alloc((size_t)NH_*2*D_*1024*2 + 4096);
  short* part = (short*)alloc((size_t)48*1024*1024);
  short* o2   = (short*)alloc((size_t)S_*E_*2);
  short* ffn  = (short*)alloc((size_t)S_*MLP_*2);
  short* xb    = (short*)alloc((size_t)S_*INP_*2);
  short* pwB   = (short*)alloc((size_t)E_*INP_*2);
  short* qkvwB = (short*)alloc((size_t)L_*3840*E_*2);
  short* prwB  = (short*)alloc((size_t)L_*E_*E_*2);
  short* f1wB  = (short*)alloc((size_t)L_*MLP_*E_*2);
  short* f2wB  = (short*)alloc((size_t)L_*E_*MLP_*2);
  short* mf1B  = (short*)alloc((size_t)H4_*H4_*2);
  short* mf2B  = (short*)alloc((size_t)O_*H4_*2);
  short* df1B  = (short*)alloc((size_t)2*H4_*H4_*2);
  short* df2B  = (short*)alloc((size_t)2*O_*H4_*2);
  size_t need = (size_t)(wsp - (char*)d_ws);
  if (need > ws_size){
    fprintf(stderr, "kernel_launch: ws too small: need %zu have %zu\n", need, ws_size);
    return;
  }
  short* dsln = qkvb;

  const dim3 B256(256);
  auto cvt = [&](const float* src, short* dst, long long n){
    unsigned blk = (unsigned)min((long long)8192, (n/8 + 255)/256);
    cvt_k<<<blk, B256, 0, stream>>>(src, dst, n);
  };
  cvt(x, xb, (long long)S_*INP_);
  cvt(patch_w, pwB, (long long)E_*INP_);
  cvt(qkv_w, qkvwB, (long long)L_*3840*E_);
  cvt(attn_proj_w, prwB, (long long)L_*E_*E_);
  cvt(fc1_w, f1wB, (long long)L_*MLP_*E_);
  cvt(fc2_w, f2wB, (long long)L_*E_*MLP_);
  cvt(m_fc1_w, mf1B, (long long)H4_*H4_);
  cvt(m_fc2_w, mf2B, (long long)O_*H4_);
  cvt(ds_fc1_w, df1B, (long long)2*H4_*H4_);
  cvt(ds_fc2_w, df2B, (long long)2*O_*H4_);

  auto G = [](int M, int N, int ks = 1){
    return dim3((unsigned)((N+127)/128), (unsigned)((M+127)/128), (unsigned)ks);
  };
  auto RG = [](long long MN){ return dim3((unsigned)((MN/8 + 255)/256)); };

  // patch embed split-K x4, fused reduce + pos-embed + ln1(layer0)
  { Gemm2P pp = mk(xb, pwB, nullptr, nullptr, INP_, INP_, E_, S_, E_, INP_);
    pp.part = part; pp.kSplit = 4;
    gemm2_k<0,false,true,true><<<G(S_,E_,4),B256,0,stream>>>(pp);
    redposln_k<<<S_, B256, 0, stream>>>(part, (long long)S_*E_, patch_b, pos_emb,
                                        h, ln1_w, ln1_b, aln); }

  for (int l = 0; l < L_; l++){
    // qkv: direct epilogue (480 blocks)
    { Gemm2P pp = mk(aln, qkvwB + (size_t)l*3840*E_, qkvb, qkv_b + l*3840, E_, E_, 3840, S_, 3840, E_);
      gemm2_k<0,false,false,false><<<G(S_,3840),B256,0,stream>>>(pp); }
    rope_k<<<(S_*NH_*40+255)/256, B256, 0, stream>>>(qkvb, qh, kh, vt);
    fattn_k<<<dim3(16,16,2), B256, 0, stream>>>(qh, kh, vt, o2);
    // attn proj split-K x4, fused reduce+residual+ln2
    { Gemm2P pp = mk(o2, prwB + (size_t)l*E_*E_, nullptr, nullptr, E_, E_, E_, S_, E_, E_);
      pp.part = part; pp.kSplit = 4;
      gemm2_k<0,false,true,true><<<G(S_,E_,4),B256,0,stream>>>(pp);
      redln_k<<<S_, B256, 0, stream>>>(part, (long long)S_*E_, attn_proj_b + l*E_,
                                       h, ln2_w + l*E_, ln2_b + l*E_, aln); }

    // MLP: fc1 direct epilogue (gelu in epilogue, 640 blocks)
    { Gemm2P pp = mk(aln, f1wB + (size_t)l*MLP_*E_, ffn, fc1_b + l*MLP_, E_, E_, MLP_, S_, MLP_, E_);
      gemm2_k<1,false,false,false><<<G(S_,MLP_),B256,0,stream>>>(pp); }
    // fc2 split-K x4, fused reduce+residual+(next ln1 | m_ln)
    { Gemm2P pp = mk(ffn, f2wB + (size_t)l*E_*MLP_, nullptr, nullptr, MLP_, MLP_, E_, S_, E_, MLP_);
      pp.part = part; pp.kSplit = 4;
      gemm2_k<0,false,true,true><<<G(S_,E_,4),B256,0,stream>>>(pp);
      const float* nw = (l < 3) ? (ln1_w + (l+1)*E_) : m_ln_w;
      const float* nb = (l < 3) ? (ln1_b + (l+1)*E_) : m_ln_b;
      redln_k<<<S_, B256, 0, stream>>>(part, (long long)S_*E_, fc2_b + l*E_, h, nw, nb, aln); }

    // deepstack mergers after layers 1 and 2
    if (l == 1 || l == 2){
      const int j = l - 1;
      ln_k<<<512, B256, 0, stream>>>(h, ds_ln_w + (size_t)j*H4_, ds_ln_b + (size_t)j*H4_, dsln, H4_);
      { Gemm2P pp = mk(dsln, df1B + (size_t)j*H4_*H4_, ffn, nullptr, H4_, H4_, H4_, 512, H4_, H4_);
        pp.part = part; pp.kSplit = 4;
        gemm2_k<0,false,false,true><<<G(512,H4_,4),B256,0,stream>>>(pp);
        reduce_k<2,false,false><<<RG((long long)512*H4_),B256,0,stream>>>(part, 4, (long long)512*H4_, H4_, ds_fc1_b + (size_t)j*H4_, ffn); }
      { Gemm2P pp = mk(ffn, df2B + (size_t)j*O_*H4_, out + (size_t)(1+j)*512*O_, nullptr, H4_, H4_, O_, 512, O_, H4_);
        pp.part = part; pp.kSplit = 8;
        gemm2_k<0,false,true,true><<<G(512,O_,8),B256,0,stream>>>(pp);
        reduce_k<0,false,true><<<RG((long long)512*O_),B256,0,stream>>>(part, 8, (long long)512*O_, O_, ds_fc2_b + (size_t)j*O_, out + (size_t)(1+j)*512*O_); }
    }
  }

  // main merger (aln holds m_ln(h) from the last fc2-redln)
  { Gemm2P pp = mk(aln, mf1B, ffn, nullptr, H4_, H4_, H4_, 512, H4_, H4_);
    pp.part = part; pp.kSplit = 4;
    gemm2_k<0,false,false,true><<<G(512,H4_,4),B256,0,stream>>>(pp);
    reduce_k<2,false,false><<<RG((long long)512*H4_),B256,0,stream>>>(part, 4, (long long)512*H4_, H4_, m_fc1_b, ffn); }
  { Gemm2P pp = mk(ffn, mf2B, out, nullptr, H4_, H4_, O_, 512, O_, H4_);
    pp.part = part; pp.kSplit = 8;
    gemm2_k<0,false,true,true><<<G(512,O_,8),B256,0,stream>>>(pp);
    reduce_k<0,false,true><<<RG((long long)512*O_),B256,0,stream>>>(part, 8, (long long)512*O_, O_, m_fc2_b, out); }
}